// Round 1
// baseline (529.355 us; speedup 1.0000x reference)
//
#include <hip/hip_runtime.h>

// CenterShift: out[n,o] = x[n] * (celu(celu((pos_j-pos_i) @ w11 + b11) @ w12 + b12) @ w13 + b13)[o]
// N = 2097152, dims 3 -> 16 -> 64 -> 64, all fp32.
//
// Round 0 baseline: one thread per point, everything in registers.
// Weights are wave-uniform -> compile-time/uniform indexing so the compiler
// uses scalar loads (s_load) + SGPR-operand v_fmac; no per-lane weight traffic.

__device__ __forceinline__ float celu1(float a) {
    // jax.nn.celu with alpha=1: x>0 ? x : expm1(x)
    return a > 0.0f ? a : __expf(a) - 1.0f;
}

__global__ __launch_bounds__(256) void centershift_kernel(
    const float* __restrict__ x,
    const float* __restrict__ pos_i,
    const float* __restrict__ pos_j,
    const float* __restrict__ w11, const float* __restrict__ b11,
    const float* __restrict__ w12, const float* __restrict__ b12,
    const float* __restrict__ w13, const float* __restrict__ b13,
    float* __restrict__ out, int n)
{
    const int tid = blockIdx.x * 256 + threadIdx.x;
    if (tid >= n) return;

    const float p0 = pos_j[3 * tid + 0] - pos_i[3 * tid + 0];
    const float p1 = pos_j[3 * tid + 1] - pos_i[3 * tid + 1];
    const float p2 = pos_j[3 * tid + 2] - pos_i[3 * tid + 2];
    const float xv = x[tid];

    // ---- layer 1: 3 -> 16, celu ----
    float h1[16];
#pragma unroll
    for (int j = 0; j < 16; ++j) {
        float a = b11[j];
        a = fmaf(p0, w11[j], a);
        a = fmaf(p1, w11[16 + j], a);
        a = fmaf(p2, w11[32 + j], a);
        h1[j] = celu1(a);
    }

    // ---- layer 2: 16 -> 64, celu (fully unrolled; h2 stays in VGPRs) ----
    float h2[64];
#pragma unroll
    for (int j = 0; j < 64; ++j) {
        float a = b12[j];
#pragma unroll
        for (int k = 0; k < 16; ++k)
            a = fmaf(h1[k], w12[k * 64 + j], a);
        h2[j] = celu1(a);
    }

    // ---- layer 3: 64 -> 64, times x, float4 stores ----
    // Rolled over 16 chunks of 4 channels to keep the hot body I-cache-resident.
    float4* outv = reinterpret_cast<float4*>(out + (size_t)tid * 64);
#pragma unroll 1
    for (int o4 = 0; o4 < 16; ++o4) {
        float a0 = b13[o4 * 4 + 0];
        float a1 = b13[o4 * 4 + 1];
        float a2 = b13[o4 * 4 + 2];
        float a3 = b13[o4 * 4 + 3];
#pragma unroll
        for (int k = 0; k < 64; ++k) {
            const float hk = h2[k];
            const float* wrow = w13 + k * 64 + o4 * 4;
            a0 = fmaf(hk, wrow[0], a0);
            a1 = fmaf(hk, wrow[1], a1);
            a2 = fmaf(hk, wrow[2], a2);
            a3 = fmaf(hk, wrow[3], a3);
        }
        float4 r;
        r.x = xv * a0;
        r.y = xv * a1;
        r.z = xv * a2;
        r.w = xv * a3;
        outv[o4] = r;
    }
}

extern "C" void kernel_launch(void* const* d_in, const int* in_sizes, int n_in,
                              void* d_out, int out_size, void* d_ws, size_t ws_size,
                              hipStream_t stream) {
    const float* x     = (const float*)d_in[0];
    const float* pos_i = (const float*)d_in[1];
    const float* pos_j = (const float*)d_in[2];
    const float* w11   = (const float*)d_in[3];
    const float* b11   = (const float*)d_in[4];
    const float* w12   = (const float*)d_in[5];
    const float* b12   = (const float*)d_in[6];
    const float* w13   = (const float*)d_in[7];
    const float* b13   = (const float*)d_in[8];
    float* out = (float*)d_out;

    const int n = in_sizes[0];  // x is [N, 1] -> flat N
    const int blocks = (n + 255) / 256;
    centershift_kernel<<<blocks, 256, 0, stream>>>(
        x, pos_i, pos_j, w11, b11, w12, b12, w13, b13, out, n);
}

// Round 2
// 187.473 us; speedup vs baseline: 2.8236x; 2.8236x over previous
//
#include <hip/hip_runtime.h>

// CenterShift: out[n,o] = x[n] * (celu(celu((pos_j-pos_i)@w11+b11)@w12+b12) @ w13 + b13)[o]
// N = 2097152, dims 3 -> 16 -> 64 -> 64, fp32 in/out.
//
// Round 2: layers 1-2 per-lane fp32 (wave-uniform weights -> s_load + SGPR FMA),
// h2 staged per-wave in LDS as f16, layer 3 via mfma_f32_16x16x32_f16 computing
// D[o,p] = W13^T x H2^T so each lane holds 4 CONSECUTIVE out channels of one
// point -> float4 stores that fully cover 64B lines (kills the 4x write
// amplification seen in round 1). Per-wave LDS tile -> no __syncthreads.

typedef __attribute__((ext_vector_type(8))) _Float16 f16x8;
typedef __attribute__((ext_vector_type(4))) float f32x4;

__device__ __forceinline__ float celu1(float a) {
    return a > 0.0f ? a : __expf(a) - 1.0f;
}

__global__ __launch_bounds__(256) void centershift_kernel(
    const float* __restrict__ x,
    const float* __restrict__ pos_i,
    const float* __restrict__ pos_j,
    const float* __restrict__ w11, const float* __restrict__ b11,
    const float* __restrict__ w12, const float* __restrict__ b12,
    const float* __restrict__ w13, const float* __restrict__ b13,
    float* __restrict__ out, int n)
{
    // per-wave h2 tile: 64 points x 64 k (f16), row stride 72 to spread banks
    __shared__ __align__(16) _Float16 smem[4][64][72];

    const int lane = threadIdx.x & 63;
    const int wid  = threadIdx.x >> 6;
    const int base = (blockIdx.x * 4 + wid) * 64;   // 64 points per wave
    if (base >= n) return;
    const int p = base + lane;

    const int g   = lane >> 4;   // k-chunk group (0..3)
    const int r16 = lane & 15;   // free-dim index within 16

    // ---- one-time: A fragments = w13^T in f16 (per-lane gathered, L2-hot) ----
    // A[row=o_local=lane&15, k=(lane>>4)*8+j]; tile u covers o = u*16 + r16.
    f16x8 afrag[4][2];
#pragma unroll
    for (int u = 0; u < 4; ++u) {
#pragma unroll
        for (int kh = 0; kh < 2; ++kh) {
            f16x8 v;
#pragma unroll
            for (int j = 0; j < 8; ++j) {
                const int k = kh * 32 + g * 8 + j;
                v[j] = (_Float16)w13[k * 64 + (u * 16 + r16)];
            }
            afrag[u][kh] = v;
        }
    }
    // bias in C/D layout: lane holds o = u*16 + g*4 + rr
    float b13v[4][4];
#pragma unroll
    for (int u = 0; u < 4; ++u)
#pragma unroll
        for (int rr = 0; rr < 4; ++rr)
            b13v[u][rr] = b13[u * 16 + g * 4 + rr];

    // ---- layer 1: 3 -> 16 (lane = point, weights wave-uniform) ----
    const float3 pi = *reinterpret_cast<const float3*>(pos_i + 3 * (size_t)p);
    const float3 pj = *reinterpret_cast<const float3*>(pos_j + 3 * (size_t)p);
    const float p0 = pj.x - pi.x, p1 = pj.y - pi.y, p2 = pj.z - pi.z;
    const float xv = x[p];

    float h1[16];
#pragma unroll
    for (int j = 0; j < 16; ++j) {
        float a = b11[j];
        a = fmaf(p0, w11[j], a);
        a = fmaf(p1, w11[16 + j], a);
        a = fmaf(p2, w11[32 + j], a);
        h1[j] = celu1(a);
    }

    // ---- layer 2: 16 -> 64, streamed to LDS as f16 in 8-element chunks ----
    _Float16* myrow = &smem[wid][lane][0];
    for (int c = 0; c < 8; ++c) {
        f16x8 v;
#pragma unroll
        for (int j = 0; j < 8; ++j) {
            const int o = c * 8 + j;
            float a = b12[o];
#pragma unroll
            for (int k = 0; k < 16; ++k)
                a = fmaf(h1[k], w12[k * 64 + o], a);
            v[j] = (_Float16)celu1(a);
        }
        *reinterpret_cast<f16x8*>(myrow + c * 8) = v;  // ds_write_b128
    }

    // ---- layer 3: MFMA, D[o,p] = W13^T x H2^T, 4 m-tiles of 16 points ----
    const _Float16* wrow = &smem[wid][0][0];
#pragma unroll
    for (int t = 0; t < 4; ++t) {
        // B frag: B[k=(g)*8+j, col=p_local=r16]; LDS row = point t*16+r16
        const _Float16* brow = wrow + (t * 16 + r16) * 72;
        const f16x8 b0 = *reinterpret_cast<const f16x8*>(brow + g * 8);
        const f16x8 b1 = *reinterpret_cast<const f16x8*>(brow + 32 + g * 8);
        const float xvt = __shfl(xv, t * 16 + r16);
        float* optr = out + (size_t)(base + t * 16 + r16) * 64;
#pragma unroll
        for (int u = 0; u < 4; ++u) {
            f32x4 acc = { b13v[u][0], b13v[u][1], b13v[u][2], b13v[u][3] };
            acc = __builtin_amdgcn_mfma_f32_16x16x32_f16(afrag[u][0], b0, acc, 0, 0, 0);
            acc = __builtin_amdgcn_mfma_f32_16x16x32_f16(afrag[u][1], b1, acc, 0, 0, 0);
            // lane holds out channels o = u*16 + g*4 + {0..3} of point base+t*16+r16
            float4 o4 = { acc[0] * xvt, acc[1] * xvt, acc[2] * xvt, acc[3] * xvt };
            *reinterpret_cast<float4*>(optr + u * 16 + g * 4) = o4;
        }
    }
}

extern "C" void kernel_launch(void* const* d_in, const int* in_sizes, int n_in,
                              void* d_out, int out_size, void* d_ws, size_t ws_size,
                              hipStream_t stream) {
    const float* x     = (const float*)d_in[0];
    const float* pos_i = (const float*)d_in[1];
    const float* pos_j = (const float*)d_in[2];
    const float* w11   = (const float*)d_in[3];
    const float* b11   = (const float*)d_in[4];
    const float* w12   = (const float*)d_in[5];
    const float* b12   = (const float*)d_in[6];
    const float* w13   = (const float*)d_in[7];
    const float* b13   = (const float*)d_in[8];
    float* out = (float*)d_out;

    const int n = in_sizes[0];                 // N (x is [N,1])
    const int blocks = (n + 255) / 256;        // 4 waves/block, 64 points/wave
    centershift_kernel<<<blocks, 256, 0, stream>>>(
        x, pos_i, pos_j, w11, b11, w12, b12, w13, b13, out, n);
}